// Round 4
// baseline (582.521 us; speedup 1.0000x reference)
//
#include <hip/hip_runtime.h>
#include <math.h>

typedef short bf16x8 __attribute__((ext_vector_type(8)));
typedef float f32x4  __attribute__((ext_vector_type(4)));
typedef unsigned short u16;
typedef unsigned int   u32;

#define MFMA16 __builtin_amdgcn_mfma_f32_16x16x32_bf16

__device__ __forceinline__ u16 f2b(float x) {   // fp32 -> bf16 RNE
    union { float f; unsigned u; } v; v.f = x;
    unsigned r = v.u + 0x7fffu + ((v.u >> 16) & 1u);
    return (u16)(r >> 16);
}
__device__ __forceinline__ float b2f(u16 h) {
    union { unsigned u; float f; } v; v.u = ((unsigned)h) << 16;
    return v.f;
}
__device__ __forceinline__ float blo(u32 w) {
    union { u32 u; float f; } v; v.u = w << 16; return v.f;
}
__device__ __forceinline__ float bhi(u32 w) {
    union { u32 u; float f; } v; v.u = w & 0xffff0000u; return v.f;
}

// ---------------------------------------------------------------------------
// K0: pre-swizzle weights (bf16, B-fragment panel layout) into global ws.
// Panel(kt,nt): 16 n-rows x 40 u16 (pad 32->40). SWZ layout:
//   WB [0,5120) | V1B [5120,15360) | V2B [15360,20480)
// ---------------------------------------------------------------------------
__global__ __launch_bounds__(256) void swizzle_weights(
    const float* __restrict__ Wg, const float* __restrict__ V1g,
    const float* __restrict__ V2g, u16* __restrict__ SWZ)
{
    int idx = blockIdx.x * 256 + threadIdx.x;       // 0..8191
    int k = idx >> 6, n = idx & 63;
    int off = ((k >> 5) * 4 + (n >> 4)) * 640 + (n & 15) * 40 + ((k >> 3) & 3) * 8 + (k & 7);
    SWZ[5120 + off] = f2b(V1g[idx]);
    if (idx < 4096) {
        SWZ[off]         = f2b(Wg[idx]);
        SWZ[15360 + off] = f2b(V2g[idx]);
    }
}

// ---------------------------------------------------------------------------
// K1: node MLP -> hb (bf16) [N,64]
// ---------------------------------------------------------------------------
__global__ __launch_bounds__(256) void node_mlp_kernel(
    const float* __restrict__ x, const float* __restrict__ u,
    const int* __restrict__ batch,
    const float* __restrict__ W1, const float* __restrict__ b1,
    const float* __restrict__ W2, const float* __restrict__ b2,
    const float* __restrict__ W3, const float* __restrict__ b3,
    u16* __restrict__ hb, int N)
{
    __shared__ float inbuf[4][10];
    __shared__ float h1[4][64];
    __shared__ float h2[4][64];
    const int tid = threadIdx.x;
    const int ni = tid >> 6, f = tid & 63;
    int node = blockIdx.x * 4 + ni;
    if (node >= N) node = N - 1;
    if (f < 6)       inbuf[ni][f] = x[node * 6 + f];
    else if (f < 10) inbuf[ni][f] = u[batch[node] * 4 + (f - 6)];
    __syncthreads();
    float acc = b1[f];
    #pragma unroll
    for (int k = 0; k < 10; ++k) acc = fmaf(inbuf[ni][k], W1[k * 64 + f], acc);
    h1[ni][f] = fmaxf(acc, 0.f);
    __syncthreads();
    acc = b2[f];
    #pragma unroll 16
    for (int k = 0; k < 64; ++k) acc = fmaf(h1[ni][k], W2[k * 64 + f], acc);
    h2[ni][f] = fmaxf(acc, 0.f);
    __syncthreads();
    acc = b3[f];
    #pragma unroll 16
    for (int k = 0; k < 64; ++k) acc = fmaf(h2[ni][k], W3[k * 64 + f], acc);
    hb[node * 64 + f] = f2b(acc);
}

// ---------------------------------------------------------------------------
// K2: segment boundaries (batch_hyper sorted)
// ---------------------------------------------------------------------------
__global__ __launch_bounds__(256) void seg_bounds_kernel(
    const int* __restrict__ bh, int E, int G, int* __restrict__ seg_start)
{
    int g = blockIdx.x * blockDim.x + threadIdx.x;
    if (g > G) return;
    int lo = 0, hi = E;
    while (lo < hi) {
        int mid = (lo + hi) >> 1;
        if (bh[mid] < g) lo = mid + 1; else hi = mid;
    }
    seg_start[g] = lo;
}

// ---------------------------------------------------------------------------
// K3: gather + Xh write + softmax denominators + out[E..2E) writes.
// 4 edges per wave-iter: sub = lane>>4 picks edge, cl = lane&15 covers 4
// feature cols via uint2 (8B). Explicit unroll-2 -> 6 row-gathers in flight.
// exp() of the ROUNDED bf16 value (must match what K4's MFMA consumes).
// ---------------------------------------------------------------------------
__global__ __launch_bounds__(256) void gather_stats_kernel(
    const u16* __restrict__ hb, const int* __restrict__ hidx,
    const int* __restrict__ seg_start,
    u16* __restrict__ Xh, float* __restrict__ Sinv,
    float* __restrict__ out, int E)
{
    __shared__ float ps[4][16][4];
    const int tid = threadIdx.x, lane = tid & 63, wid = tid >> 6;
    const int sub = lane >> 4, cl = lane & 15;
    const int g = blockIdx.x;
    const int e0 = seg_start[g], e1 = seg_start[g + 1];
    if (e1 <= e0) return;
    const float gf = (float)g;

    for (int e = e0 + tid; e < e1; e += 256) out[E + e] = gf;   // coalesced

    float s0 = 0.f, s1 = 0.f, s2 = 0.f, s3 = 0.f;
    const int base = e0 + wid * 4 + sub;

    for (int e = base; e < e1; e += 32) {
        int eb = e + 16;
        bool h2v = (eb < e1);
        int ai0 = hidx[e], ai1 = hidx[E + e], ai2 = hidx[2 * E + e];
        int bi0 = 0, bi1 = 0, bi2 = 0;
        if (h2v) { bi0 = hidx[eb]; bi1 = hidx[E + eb]; bi2 = hidx[2 * E + eb]; }
        uint2 A0 = *(const uint2*)(hb + (size_t)ai0 * 64 + cl * 4);
        uint2 A1 = *(const uint2*)(hb + (size_t)ai1 * 64 + cl * 4);
        uint2 A2 = *(const uint2*)(hb + (size_t)ai2 * 64 + cl * 4);
        uint2 B0, B1, B2;
        if (h2v) {
            B0 = *(const uint2*)(hb + (size_t)bi0 * 64 + cl * 4);
            B1 = *(const uint2*)(hb + (size_t)bi1 * 64 + cl * 4);
            B2 = *(const uint2*)(hb + (size_t)bi2 * 64 + cl * 4);
        }
        {
            float v0 = blo(A0.x) + blo(A1.x) + blo(A2.x);
            float v1 = bhi(A0.x) + bhi(A1.x) + bhi(A2.x);
            float v2 = blo(A0.y) + blo(A1.y) + blo(A2.y);
            float v3 = bhi(A0.y) + bhi(A1.y) + bhi(A2.y);
            u16 r0 = f2b(v0), r1 = f2b(v1), r2 = f2b(v2), r3 = f2b(v3);
            uint2 W; W.x = (u32)r0 | ((u32)r1 << 16); W.y = (u32)r2 | ((u32)r3 << 16);
            *(uint2*)(Xh + (size_t)e * 64 + cl * 4) = W;
            s0 += __expf(b2f(r0)); s1 += __expf(b2f(r1));
            s2 += __expf(b2f(r2)); s3 += __expf(b2f(r3));
        }
        if (h2v) {
            float v0 = blo(B0.x) + blo(B1.x) + blo(B2.x);
            float v1 = bhi(B0.x) + bhi(B1.x) + bhi(B2.x);
            float v2 = blo(B0.y) + blo(B1.y) + blo(B2.y);
            float v3 = bhi(B0.y) + bhi(B1.y) + bhi(B2.y);
            u16 r0 = f2b(v0), r1 = f2b(v1), r2 = f2b(v2), r3 = f2b(v3);
            uint2 W; W.x = (u32)r0 | ((u32)r1 << 16); W.y = (u32)r2 | ((u32)r3 << 16);
            *(uint2*)(Xh + (size_t)eb * 64 + cl * 4) = W;
            s0 += __expf(b2f(r0)); s1 += __expf(b2f(r1));
            s2 += __expf(b2f(r2)); s3 += __expf(b2f(r3));
        }
    }
    // reduce over sub (lane bits 4,5) then over waves
    s0 += __shfl_xor(s0, 16); s0 += __shfl_xor(s0, 32);
    s1 += __shfl_xor(s1, 16); s1 += __shfl_xor(s1, 32);
    s2 += __shfl_xor(s2, 16); s2 += __shfl_xor(s2, 32);
    s3 += __shfl_xor(s3, 16); s3 += __shfl_xor(s3, 32);
    if (lane < 16) {
        ps[wid][cl][0] = s0; ps[wid][cl][1] = s1;
        ps[wid][cl][2] = s2; ps[wid][cl][3] = s3;
    }
    __syncthreads();
    if (tid < 64) {
        int c4 = tid >> 2, cc = tid & 3;
        float S = ps[0][c4][cc] + ps[1][c4][cc] + ps[2][c4][cc] + ps[3][c4][cc];
        Sinv[g * 64 + tid] = 1.f / S;
    }
}

// ---------------------------------------------------------------------------
// K4: MFMA chain per segment.
//  - V2 B-frags in REGISTERS (loop-invariant, loaded once from SWZ).
//  - next-tile Xh a-frags prefetched (HBM latency off the chain).
//  - xv (X in C-layout) via identity-MFMA (exact), no XT round trip for X.
//  - XT used only for Xhat and O1 C->A transposes (wave-private, stride 72).
// LDS: 30720(SW) + 9216(XT) = 39936 B -> 4 blocks/CU.
// ---------------------------------------------------------------------------
__global__ __launch_bounds__(256, 4) void mfma_seg_kernel(
    const u16* __restrict__ Xh, const int* __restrict__ seg_start,
    const u16* __restrict__ SWZ, const float* __restrict__ Sinv,
    const float* __restrict__ c1g, const float* __restrict__ c2g,
    const float* __restrict__ V3g, const float* __restrict__ c3g,
    float* __restrict__ out, int E)
{
    __shared__ u16 SW[15360];          // WB [0,5120) + V1B [5120,15360)
    __shared__ u16 XT_all[4][16 * 72]; // per-wave transpose tile

    const int tid = threadIdx.x, lane = tid & 63, wid = tid >> 6;
    const int nl = lane & 15, rq = lane >> 4;
    const int g = blockIdx.x;
    const int e0 = seg_start[g], e1 = seg_start[g + 1];
    const int L = e1 - e0;
    if (L <= 0) return;
    const int e1m1 = e1 - 1;

    {   // stage pre-swizzled W+V1: 30720 B = 1920 uint4
        const uint4* src = (const uint4*)SWZ;
        uint4* dst = (uint4*)SW;
        for (int i = tid; i < 1920; i += 256) dst[i] = src[i];
    }
    __syncthreads();
    const u16* WB  = SW;
    const u16* V1B = SW + 5120;

    // V2 B-frags: loop-invariant -> registers (8 x 4 VGPR)
    bf16x8 v2f[8];
    #pragma unroll
    for (int p = 0; p < 8; ++p)
        v2f[p] = *(const bf16x8*)(SWZ + 15360 + p * 640 + nl * 40 + rq * 8);

    // identity B-frags for X C-layout redistribution (exact in bf16)
    bf16x8 I0, I1;
    #pragma unroll
    for (int j = 0; j < 8; ++j) {
        I0[j] = (rq * 8 + j == nl)      ? (short)0x3F80 : (short)0;
        I1[j] = (rq * 8 + j == nl + 16) ? (short)0x3F80 : (short)0;
    }

    float dinvv[4], c1v[4], c2v[4], v3v[4];
    #pragma unroll
    for (int nt = 0; nt < 4; ++nt) {
        int col = nt * 16 + nl;
        dinvv[nt] = Sinv[g * 64 + col];
        c1v[nt]   = c1g[col];
        c2v[nt]   = c2g[col];
        v3v[nt]   = V3g[col];
    }
    const float c3s = c3g[0];
    u16* XT = XT_all[wid];
    const f32x4 zf = {0.f, 0.f, 0.f, 0.f};

    int t = wid;
    bf16x8 a0 = {}, a1 = {};
    if (t * 16 < L) {
        const u16* xp = Xh + (size_t)min(e0 + t * 16 + nl, e1m1) * 64 + rq * 8;
        a0 = *(const bf16x8*)(xp);
        a1 = *(const bf16x8*)(xp + 32);
    }

    for (; t * 16 < L; t += 4) {
        const int eB = e0 + t * 16;
        const int tn = t + 4;
        bf16x8 n0 = {}, n1 = {};
        if (tn * 16 < L) {  // prefetch next tile (wave-uniform branch)
            const u16* xp = Xh + (size_t)min(e0 + tn * 16 + nl, e1m1) * 64 + rq * 8;
            n0 = *(const bf16x8*)(xp);
            n1 = *(const bf16x8*)(xp + 32);
        }

        // xv in C-layout via identity MFMA (matrix pipe, overlaps layer W)
        f32x4 xc[4];
        xc[0] = MFMA16(a0, I0, zf, 0, 0, 0);
        xc[1] = MFMA16(a0, I1, zf, 0, 0, 0);
        xc[2] = MFMA16(a1, I0, zf, 0, 0, 0);
        xc[3] = MFMA16(a1, I1, zf, 0, 0, 0);

        // ---- layer W: acc = X @ W ----
        f32x4 acc[4] = {zf, zf, zf, zf};
        #pragma unroll
        for (int nt = 0; nt < 4; ++nt) {
            bf16x8 b0 = *(const bf16x8*)(WB + (0 * 4 + nt) * 640 + nl * 40 + rq * 8);
            acc[nt] = MFMA16(a0, b0, acc[nt], 0, 0, 0);
            bf16x8 b1 = *(const bf16x8*)(WB + (1 * 4 + nt) * 640 + nl * 40 + rq * 8);
            acc[nt] = MFMA16(a1, b1, acc[nt], 0, 0, 0);
        }
        // epilogue: Xhat = exp(xv)*dinv * relu(acc) -> XT
        #pragma unroll
        for (int nt = 0; nt < 4; ++nt) {
            #pragma unroll
            for (int r = 0; r < 4; ++r) {
                float coef = __expf(xc[nt][r]) * dinvv[nt];
                XT[(rq * 4 + r) * 72 + nt * 16 + nl] =
                    f2b(coef * fmaxf(acc[nt][r], 0.f));
            }
        }
        bf16x8 x2 = *(const bf16x8*)(XT + nl * 72 + rq * 8);
        bf16x8 x3 = *(const bf16x8*)(XT + nl * 72 + 32 + rq * 8);

        // ---- layer V1: acc2 = [X ; Xhat] @ V1 + c1 ----
        f32x4 acc2[4];
        #pragma unroll
        for (int nt = 0; nt < 4; ++nt) {
            acc2[nt][0] = c1v[nt]; acc2[nt][1] = c1v[nt];
            acc2[nt][2] = c1v[nt]; acc2[nt][3] = c1v[nt];
        }
        #pragma unroll
        for (int nt = 0; nt < 4; ++nt) {
            bf16x8 b0 = *(const bf16x8*)(V1B + (0 * 4 + nt) * 640 + nl * 40 + rq * 8);
            acc2[nt] = MFMA16(a0, b0, acc2[nt], 0, 0, 0);
            bf16x8 b1 = *(const bf16x8*)(V1B + (1 * 4 + nt) * 640 + nl * 40 + rq * 8);
            acc2[nt] = MFMA16(a1, b1, acc2[nt], 0, 0, 0);
        }
        #pragma unroll
        for (int nt = 0; nt < 4; ++nt) {
            bf16x8 b2 = *(const bf16x8*)(V1B + (2 * 4 + nt) * 640 + nl * 40 + rq * 8);
            acc2[nt] = MFMA16(x2, b2, acc2[nt], 0, 0, 0);
            bf16x8 b3 = *(const bf16x8*)(V1B + (3 * 4 + nt) * 640 + nl * 40 + rq * 8);
            acc2[nt] = MFMA16(x3, b3, acc2[nt], 0, 0, 0);
        }
        // epilogue: O1 = relu(acc2) -> XT
        #pragma unroll
        for (int nt = 0; nt < 4; ++nt) {
            #pragma unroll
            for (int r = 0; r < 4; ++r)
                XT[(rq * 4 + r) * 72 + nt * 16 + nl] = f2b(fmaxf(acc2[nt][r], 0.f));
        }
        bf16x8 o0 = *(const bf16x8*)(XT + nl * 72 + rq * 8);
        bf16x8 o1 = *(const bf16x8*)(XT + nl * 72 + 32 + rq * 8);

        // ---- layer V2: acc3 = O1 @ V2 + c2 (B-frags in registers) ----
        f32x4 acc3[4];
        #pragma unroll
        for (int nt = 0; nt < 4; ++nt) {
            acc3[nt][0] = c2v[nt]; acc3[nt][1] = c2v[nt];
            acc3[nt][2] = c2v[nt]; acc3[nt][3] = c2v[nt];
        }
        #pragma unroll
        for (int nt = 0; nt < 4; ++nt) {
            acc3[nt] = MFMA16(o0, v2f[0 * 4 + nt], acc3[nt], 0, 0, 0);
            acc3[nt] = MFMA16(o1, v2f[1 * 4 + nt], acc3[nt], 0, 0, 0);
        }

        // ---- V3 + sigmoid ----
        float sr[4];
        #pragma unroll
        for (int r = 0; r < 4; ++r) {
            float v = 0.f;
            #pragma unroll
            for (int nt = 0; nt < 4; ++nt)
                v = fmaf(fmaxf(acc3[nt][r], 0.f), v3v[nt], v);
            v += __shfl_xor(v, 1);
            v += __shfl_xor(v, 2);
            v += __shfl_xor(v, 4);
            v += __shfl_xor(v, 8);
            sr[r] = v;
        }
        if (nl == 0) {
            #pragma unroll
            for (int r = 0; r < 4; ++r) {
                int e = eB + rq * 4 + r;
                if (e < e1) out[e] = 1.f / (1.f + __expf(-(sr[r] + c3s)));
            }
        }
        a0 = n0; a1 = n1;
    }
}

// ---------------------------------------------------------------------------
extern "C" void kernel_launch(void* const* d_in, const int* in_sizes, int n_in,
                              void* d_out, int out_size, void* d_ws, size_t ws_size,
                              hipStream_t stream) {
    const float* x     = (const float*)d_in[0];
    const float* u     = (const float*)d_in[1];
    const int*   batch = (const int*)  d_in[2];
    const int*   hidx  = (const int*)  d_in[3];
    const int*   bh    = (const int*)  d_in[4];
    const float* W1 = (const float*)d_in[6];
    const float* b1 = (const float*)d_in[7];
    const float* W2 = (const float*)d_in[8];
    const float* b2 = (const float*)d_in[9];
    const float* W3 = (const float*)d_in[10];
    const float* b3 = (const float*)d_in[11];
    const float* Wg = (const float*)d_in[12];
    const float* V1 = (const float*)d_in[13];
    const float* c1 = (const float*)d_in[14];
    const float* V2 = (const float*)d_in[15];
    const float* c2 = (const float*)d_in[16];
    const float* V3 = (const float*)d_in[17];
    const float* c3 = (const float*)d_in[18];

    const int N = in_sizes[0] / 6;
    const int G = in_sizes[1] / 4;
    const int E = in_sizes[4];

    // ws layout
    char* ws = (char*)d_ws;
    size_t off = 0;
    u16* hb = (u16*)(ws + off);            off += (size_t)N * 64 * 2;
    int* seg_start = (int*)(ws + off);     off += ((size_t)G + 1) * 4;
    off = (off + 255) & ~(size_t)255;
    u16* SWZ = (u16*)(ws + off);           off += 20480 * 2;
    float* Sinv = (float*)(ws + off);      off += (size_t)G * 64 * 4;
    off = (off + 255) & ~(size_t)255;
    u16* Xh = (u16*)(ws + off);            off += (size_t)E * 64 * 2;
    float* out = (float*)d_out;

    swizzle_weights<<<32, 256, 0, stream>>>(Wg, V1, V2, SWZ);
    node_mlp_kernel<<<(N + 3) / 4, 256, 0, stream>>>(
        x, u, batch, W1, b1, W2, b2, W3, b3, hb, N);
    seg_bounds_kernel<<<(G + 256) / 256, 256, 0, stream>>>(bh, E, G, seg_start);
    gather_stats_kernel<<<G, 256, 0, stream>>>(hb, hidx, seg_start, Xh, Sinv, out, E);
    mfma_seg_kernel<<<G, 256, 0, stream>>>(
        Xh, seg_start, SWZ, Sinv, c1, c2, V3, c3, out, E);
}

// Round 5
// 471.879 us; speedup vs baseline: 1.2345x; 1.2345x over previous
//
#include <hip/hip_runtime.h>
#include <math.h>

typedef short bf16x8 __attribute__((ext_vector_type(8)));
typedef float f32x4  __attribute__((ext_vector_type(4)));
typedef unsigned short u16;
typedef unsigned int   u32;

#define MFMA16 __builtin_amdgcn_mfma_f32_16x16x32_bf16

__device__ __forceinline__ u16 f2b(float x) {   // fp32 -> bf16 RNE
    union { float f; unsigned u; } v; v.f = x;
    unsigned r = v.u + 0x7fffu + ((v.u >> 16) & 1u);
    return (u16)(r >> 16);
}
__device__ __forceinline__ float b2f(u16 h) {
    union { unsigned u; float f; } v; v.u = ((unsigned)h) << 16;
    return v.f;
}
__device__ __forceinline__ float blo(u32 w) {
    union { u32 u; float f; } v; v.u = w << 16; return v.f;
}
__device__ __forceinline__ float bhi(u32 w) {
    union { u32 u; float f; } v; v.u = w & 0xffff0000u; return v.f;
}

// ---------------------------------------------------------------------------
// K0: pre-swizzle weights (bf16, B-fragment panel layout) into global ws.
// Panel(kt,nt): 16 n-rows x 40 u16 (pad 32->40). SWZ layout:
//   WB [0,5120) | V1B [5120,15360) | V2B [15360,20480)
// ---------------------------------------------------------------------------
__global__ __launch_bounds__(256) void swizzle_weights(
    const float* __restrict__ Wg, const float* __restrict__ V1g,
    const float* __restrict__ V2g, u16* __restrict__ SWZ)
{
    int idx = blockIdx.x * 256 + threadIdx.x;       // 0..8191
    int k = idx >> 6, n = idx & 63;
    int off = ((k >> 5) * 4 + (n >> 4)) * 640 + (n & 15) * 40 + ((k >> 3) & 3) * 8 + (k & 7);
    SWZ[5120 + off] = f2b(V1g[idx]);
    if (idx < 4096) {
        SWZ[off]         = f2b(Wg[idx]);
        SWZ[15360 + off] = f2b(V2g[idx]);
    }
}

// ---------------------------------------------------------------------------
// K1: node MLP -> hb (bf16) [N,64]
// ---------------------------------------------------------------------------
__global__ __launch_bounds__(256) void node_mlp_kernel(
    const float* __restrict__ x, const float* __restrict__ u,
    const int* __restrict__ batch,
    const float* __restrict__ W1, const float* __restrict__ b1,
    const float* __restrict__ W2, const float* __restrict__ b2,
    const float* __restrict__ W3, const float* __restrict__ b3,
    u16* __restrict__ hb, int N)
{
    __shared__ float inbuf[4][10];
    __shared__ float h1[4][64];
    __shared__ float h2[4][64];
    const int tid = threadIdx.x;
    const int ni = tid >> 6, f = tid & 63;
    int node = blockIdx.x * 4 + ni;
    if (node >= N) node = N - 1;
    if (f < 6)       inbuf[ni][f] = x[node * 6 + f];
    else if (f < 10) inbuf[ni][f] = u[batch[node] * 4 + (f - 6)];
    __syncthreads();
    float acc = b1[f];
    #pragma unroll
    for (int k = 0; k < 10; ++k) acc = fmaf(inbuf[ni][k], W1[k * 64 + f], acc);
    h1[ni][f] = fmaxf(acc, 0.f);
    __syncthreads();
    acc = b2[f];
    #pragma unroll 16
    for (int k = 0; k < 64; ++k) acc = fmaf(h1[ni][k], W2[k * 64 + f], acc);
    h2[ni][f] = fmaxf(acc, 0.f);
    __syncthreads();
    acc = b3[f];
    #pragma unroll 16
    for (int k = 0; k < 64; ++k) acc = fmaf(h2[ni][k], W3[k * 64 + f], acc);
    hb[node * 64 + f] = f2b(acc);
}

// ---------------------------------------------------------------------------
// K2: segment boundaries (batch_hyper sorted)
// ---------------------------------------------------------------------------
__global__ __launch_bounds__(256) void seg_bounds_kernel(
    const int* __restrict__ bh, int E, int G, int* __restrict__ seg_start)
{
    int g = blockIdx.x * blockDim.x + threadIdx.x;
    if (g > G) return;
    int lo = 0, hi = E;
    while (lo < hi) {
        int mid = (lo + hi) >> 1;
        if (bh[mid] < g) lo = mid + 1; else hi = mid;
    }
    seg_start[g] = lo;
}

// ---------------------------------------------------------------------------
// K3: gather + Xh write + softmax denominators + out[E..2E) writes.
// 4 edges per wave-iter: sub = lane>>4 picks edge, cl = lane&15 covers 4
// feature cols via uint2 (8B). Explicit unroll-2 -> 6 row-gathers in flight.
// exp() of the ROUNDED bf16 value (must match what K4's MFMA consumes).
// ---------------------------------------------------------------------------
__global__ __launch_bounds__(256) void gather_stats_kernel(
    const u16* __restrict__ hb, const int* __restrict__ hidx,
    const int* __restrict__ seg_start,
    u16* __restrict__ Xh, float* __restrict__ Sinv,
    float* __restrict__ out, int E)
{
    __shared__ float ps[4][16][4];
    const int tid = threadIdx.x, lane = tid & 63, wid = tid >> 6;
    const int sub = lane >> 4, cl = lane & 15;
    const int g = blockIdx.x;
    const int e0 = seg_start[g], e1 = seg_start[g + 1];
    if (e1 <= e0) return;
    const float gf = (float)g;

    for (int e = e0 + tid; e < e1; e += 256) out[E + e] = gf;   // coalesced

    float s0 = 0.f, s1 = 0.f, s2 = 0.f, s3 = 0.f;
    const int base = e0 + wid * 4 + sub;

    for (int e = base; e < e1; e += 32) {
        int eb = e + 16;
        bool h2v = (eb < e1);
        int ai0 = hidx[e], ai1 = hidx[E + e], ai2 = hidx[2 * E + e];
        int bi0 = 0, bi1 = 0, bi2 = 0;
        if (h2v) { bi0 = hidx[eb]; bi1 = hidx[E + eb]; bi2 = hidx[2 * E + eb]; }
        uint2 A0 = *(const uint2*)(hb + (size_t)ai0 * 64 + cl * 4);
        uint2 A1 = *(const uint2*)(hb + (size_t)ai1 * 64 + cl * 4);
        uint2 A2 = *(const uint2*)(hb + (size_t)ai2 * 64 + cl * 4);
        uint2 B0, B1, B2;
        if (h2v) {
            B0 = *(const uint2*)(hb + (size_t)bi0 * 64 + cl * 4);
            B1 = *(const uint2*)(hb + (size_t)bi1 * 64 + cl * 4);
            B2 = *(const uint2*)(hb + (size_t)bi2 * 64 + cl * 4);
        }
        {
            float v0 = blo(A0.x) + blo(A1.x) + blo(A2.x);
            float v1 = bhi(A0.x) + bhi(A1.x) + bhi(A2.x);
            float v2 = blo(A0.y) + blo(A1.y) + blo(A2.y);
            float v3 = bhi(A0.y) + bhi(A1.y) + bhi(A2.y);
            u16 r0 = f2b(v0), r1 = f2b(v1), r2 = f2b(v2), r3 = f2b(v3);
            uint2 W; W.x = (u32)r0 | ((u32)r1 << 16); W.y = (u32)r2 | ((u32)r3 << 16);
            *(uint2*)(Xh + (size_t)e * 64 + cl * 4) = W;
            s0 += __expf(b2f(r0)); s1 += __expf(b2f(r1));
            s2 += __expf(b2f(r2)); s3 += __expf(b2f(r3));
        }
        if (h2v) {
            float v0 = blo(B0.x) + blo(B1.x) + blo(B2.x);
            float v1 = bhi(B0.x) + bhi(B1.x) + bhi(B2.x);
            float v2 = blo(B0.y) + blo(B1.y) + blo(B2.y);
            float v3 = bhi(B0.y) + bhi(B1.y) + bhi(B2.y);
            u16 r0 = f2b(v0), r1 = f2b(v1), r2 = f2b(v2), r3 = f2b(v3);
            uint2 W; W.x = (u32)r0 | ((u32)r1 << 16); W.y = (u32)r2 | ((u32)r3 << 16);
            *(uint2*)(Xh + (size_t)eb * 64 + cl * 4) = W;
            s0 += __expf(b2f(r0)); s1 += __expf(b2f(r1));
            s2 += __expf(b2f(r2)); s3 += __expf(b2f(r3));
        }
    }
    // reduce over sub (lane bits 4,5) then over waves
    s0 += __shfl_xor(s0, 16); s0 += __shfl_xor(s0, 32);
    s1 += __shfl_xor(s1, 16); s1 += __shfl_xor(s1, 32);
    s2 += __shfl_xor(s2, 16); s2 += __shfl_xor(s2, 32);
    s3 += __shfl_xor(s3, 16); s3 += __shfl_xor(s3, 32);
    if (lane < 16) {
        ps[wid][cl][0] = s0; ps[wid][cl][1] = s1;
        ps[wid][cl][2] = s2; ps[wid][cl][3] = s3;
    }
    __syncthreads();
    if (tid < 64) {
        int c4 = tid >> 2, cc = tid & 3;
        float S = ps[0][c4][cc] + ps[1][c4][cc] + ps[2][c4][cc] + ps[3][c4][cc];
        Sinv[g * 64 + tid] = 1.f / S;
    }
}

// ---------------------------------------------------------------------------
// K4: MFMA chain per segment.
//  - V2 B-frags in REGISTERS (loop-invariant, loaded once from SWZ).
//  - next-tile Xh a-frags prefetched (HBM latency off the chain).
//  - xv (X in C-layout) via identity-MFMA (exact), no XT round trip for X.
//  - XT used only for Xhat and O1 C->A transposes (wave-private, stride 72).
// LDS: 30720(SW) + 9216(XT) = 39936 B.
// __launch_bounds__(256,3): R4's (256,4) capped the unified reg budget at
// 128/wave while loop live-set is ~150 -> scratch spill (FETCH 783MB->1.1GB,
// 13KB/tile of refills). 3 waves/EU gives ~170 regs -> no spill; LDS would
// allow 4 blocks/CU but VGPRs limit to 3 (12 waves, same band as R3's 42%).
// ---------------------------------------------------------------------------
__global__ __launch_bounds__(256, 3) void mfma_seg_kernel(
    const u16* __restrict__ Xh, const int* __restrict__ seg_start,
    const u16* __restrict__ SWZ, const float* __restrict__ Sinv,
    const float* __restrict__ c1g, const float* __restrict__ c2g,
    const float* __restrict__ V3g, const float* __restrict__ c3g,
    float* __restrict__ out, int E)
{
    __shared__ u16 SW[15360];          // WB [0,5120) + V1B [5120,15360)
    __shared__ u16 XT_all[4][16 * 72]; // per-wave transpose tile

    const int tid = threadIdx.x, lane = tid & 63, wid = tid >> 6;
    const int nl = lane & 15, rq = lane >> 4;
    const int g = blockIdx.x;
    const int e0 = seg_start[g], e1 = seg_start[g + 1];
    const int L = e1 - e0;
    if (L <= 0) return;
    const int e1m1 = e1 - 1;

    {   // stage pre-swizzled W+V1: 30720 B = 1920 uint4
        const uint4* src = (const uint4*)SWZ;
        uint4* dst = (uint4*)SW;
        for (int i = tid; i < 1920; i += 256) dst[i] = src[i];
    }
    __syncthreads();
    const u16* WB  = SW;
    const u16* V1B = SW + 5120;

    // V2 B-frags: loop-invariant -> registers (8 x 4 VGPR)
    bf16x8 v2f[8];
    #pragma unroll
    for (int p = 0; p < 8; ++p)
        v2f[p] = *(const bf16x8*)(SWZ + 15360 + p * 640 + nl * 40 + rq * 8);

    // identity B-frags for X C-layout redistribution (exact in bf16)
    bf16x8 I0, I1;
    #pragma unroll
    for (int j = 0; j < 8; ++j) {
        I0[j] = (rq * 8 + j == nl)      ? (short)0x3F80 : (short)0;
        I1[j] = (rq * 8 + j == nl + 16) ? (short)0x3F80 : (short)0;
    }

    float dinvv[4], c1v[4], c2v[4], v3v[4];
    #pragma unroll
    for (int nt = 0; nt < 4; ++nt) {
        int col = nt * 16 + nl;
        dinvv[nt] = Sinv[g * 64 + col];
        c1v[nt]   = c1g[col];
        c2v[nt]   = c2g[col];
        v3v[nt]   = V3g[col];
    }
    const float c3s = c3g[0];
    u16* XT = XT_all[wid];
    const f32x4 zf = {0.f, 0.f, 0.f, 0.f};

    int t = wid;
    bf16x8 a0 = {}, a1 = {};
    if (t * 16 < L) {
        const u16* xp = Xh + (size_t)min(e0 + t * 16 + nl, e1m1) * 64 + rq * 8;
        a0 = *(const bf16x8*)(xp);
        a1 = *(const bf16x8*)(xp + 32);
    }

    for (; t * 16 < L; t += 4) {
        const int eB = e0 + t * 16;
        const int tn = t + 4;
        bf16x8 n0 = {}, n1 = {};
        if (tn * 16 < L) {  // prefetch next tile (wave-uniform branch)
            const u16* xp = Xh + (size_t)min(e0 + tn * 16 + nl, e1m1) * 64 + rq * 8;
            n0 = *(const bf16x8*)(xp);
            n1 = *(const bf16x8*)(xp + 32);
        }

        // xv in C-layout via identity MFMA (matrix pipe, overlaps layer W)
        f32x4 xc[4];
        xc[0] = MFMA16(a0, I0, zf, 0, 0, 0);
        xc[1] = MFMA16(a0, I1, zf, 0, 0, 0);
        xc[2] = MFMA16(a1, I0, zf, 0, 0, 0);
        xc[3] = MFMA16(a1, I1, zf, 0, 0, 0);

        // ---- layer W: acc = X @ W ----
        f32x4 acc[4] = {zf, zf, zf, zf};
        #pragma unroll
        for (int nt = 0; nt < 4; ++nt) {
            bf16x8 b0 = *(const bf16x8*)(WB + (0 * 4 + nt) * 640 + nl * 40 + rq * 8);
            acc[nt] = MFMA16(a0, b0, acc[nt], 0, 0, 0);
            bf16x8 b1 = *(const bf16x8*)(WB + (1 * 4 + nt) * 640 + nl * 40 + rq * 8);
            acc[nt] = MFMA16(a1, b1, acc[nt], 0, 0, 0);
        }
        // epilogue: Xhat = exp(xv)*dinv * relu(acc) -> XT
        #pragma unroll
        for (int nt = 0; nt < 4; ++nt) {
            #pragma unroll
            for (int r = 0; r < 4; ++r) {
                float coef = __expf(xc[nt][r]) * dinvv[nt];
                XT[(rq * 4 + r) * 72 + nt * 16 + nl] =
                    f2b(coef * fmaxf(acc[nt][r], 0.f));
            }
        }
        bf16x8 x2 = *(const bf16x8*)(XT + nl * 72 + rq * 8);
        bf16x8 x3 = *(const bf16x8*)(XT + nl * 72 + 32 + rq * 8);

        // ---- layer V1: acc2 = [X ; Xhat] @ V1 + c1 ----
        f32x4 acc2[4];
        #pragma unroll
        for (int nt = 0; nt < 4; ++nt) {
            acc2[nt][0] = c1v[nt]; acc2[nt][1] = c1v[nt];
            acc2[nt][2] = c1v[nt]; acc2[nt][3] = c1v[nt];
        }
        #pragma unroll
        for (int nt = 0; nt < 4; ++nt) {
            bf16x8 b0 = *(const bf16x8*)(V1B + (0 * 4 + nt) * 640 + nl * 40 + rq * 8);
            acc2[nt] = MFMA16(a0, b0, acc2[nt], 0, 0, 0);
            bf16x8 b1 = *(const bf16x8*)(V1B + (1 * 4 + nt) * 640 + nl * 40 + rq * 8);
            acc2[nt] = MFMA16(a1, b1, acc2[nt], 0, 0, 0);
        }
        #pragma unroll
        for (int nt = 0; nt < 4; ++nt) {
            bf16x8 b2 = *(const bf16x8*)(V1B + (2 * 4 + nt) * 640 + nl * 40 + rq * 8);
            acc2[nt] = MFMA16(x2, b2, acc2[nt], 0, 0, 0);
            bf16x8 b3 = *(const bf16x8*)(V1B + (3 * 4 + nt) * 640 + nl * 40 + rq * 8);
            acc2[nt] = MFMA16(x3, b3, acc2[nt], 0, 0, 0);
        }
        // epilogue: O1 = relu(acc2) -> XT
        #pragma unroll
        for (int nt = 0; nt < 4; ++nt) {
            #pragma unroll
            for (int r = 0; r < 4; ++r)
                XT[(rq * 4 + r) * 72 + nt * 16 + nl] = f2b(fmaxf(acc2[nt][r], 0.f));
        }
        bf16x8 o0 = *(const bf16x8*)(XT + nl * 72 + rq * 8);
        bf16x8 o1 = *(const bf16x8*)(XT + nl * 72 + 32 + rq * 8);

        // ---- layer V2: acc3 = O1 @ V2 + c2 (B-frags in registers) ----
        f32x4 acc3[4];
        #pragma unroll
        for (int nt = 0; nt < 4; ++nt) {
            acc3[nt][0] = c2v[nt]; acc3[nt][1] = c2v[nt];
            acc3[nt][2] = c2v[nt]; acc3[nt][3] = c2v[nt];
        }
        #pragma unroll
        for (int nt = 0; nt < 4; ++nt) {
            acc3[nt] = MFMA16(o0, v2f[0 * 4 + nt], acc3[nt], 0, 0, 0);
            acc3[nt] = MFMA16(o1, v2f[1 * 4 + nt], acc3[nt], 0, 0, 0);
        }

        // ---- V3 + sigmoid ----
        float sr[4];
        #pragma unroll
        for (int r = 0; r < 4; ++r) {
            float v = 0.f;
            #pragma unroll
            for (int nt = 0; nt < 4; ++nt)
                v = fmaf(fmaxf(acc3[nt][r], 0.f), v3v[nt], v);
            v += __shfl_xor(v, 1);
            v += __shfl_xor(v, 2);
            v += __shfl_xor(v, 4);
            v += __shfl_xor(v, 8);
            sr[r] = v;
        }
        if (nl == 0) {
            #pragma unroll
            for (int r = 0; r < 4; ++r) {
                int e = eB + rq * 4 + r;
                if (e < e1) out[e] = 1.f / (1.f + __expf(-(sr[r] + c3s)));
            }
        }
        a0 = n0; a1 = n1;
    }
}

// ---------------------------------------------------------------------------
extern "C" void kernel_launch(void* const* d_in, const int* in_sizes, int n_in,
                              void* d_out, int out_size, void* d_ws, size_t ws_size,
                              hipStream_t stream) {
    const float* x     = (const float*)d_in[0];
    const float* u     = (const float*)d_in[1];
    const int*   batch = (const int*)  d_in[2];
    const int*   hidx  = (const int*)  d_in[3];
    const int*   bh    = (const int*)  d_in[4];
    const float* W1 = (const float*)d_in[6];
    const float* b1 = (const float*)d_in[7];
    const float* W2 = (const float*)d_in[8];
    const float* b2 = (const float*)d_in[9];
    const float* W3 = (const float*)d_in[10];
    const float* b3 = (const float*)d_in[11];
    const float* Wg = (const float*)d_in[12];
    const float* V1 = (const float*)d_in[13];
    const float* c1 = (const float*)d_in[14];
    const float* V2 = (const float*)d_in[15];
    const float* c2 = (const float*)d_in[16];
    const float* V3 = (const float*)d_in[17];
    const float* c3 = (const float*)d_in[18];

    const int N = in_sizes[0] / 6;
    const int G = in_sizes[1] / 4;
    const int E = in_sizes[4];

    // ws layout
    char* ws = (char*)d_ws;
    size_t off = 0;
    u16* hb = (u16*)(ws + off);            off += (size_t)N * 64 * 2;
    int* seg_start = (int*)(ws + off);     off += ((size_t)G + 1) * 4;
    off = (off + 255) & ~(size_t)255;
    u16* SWZ = (u16*)(ws + off);           off += 20480 * 2;
    float* Sinv = (float*)(ws + off);      off += (size_t)G * 64 * 4;
    off = (off + 255) & ~(size_t)255;
    u16* Xh = (u16*)(ws + off);            off += (size_t)E * 64 * 2;
    float* out = (float*)d_out;

    swizzle_weights<<<32, 256, 0, stream>>>(Wg, V1, V2, SWZ);
    node_mlp_kernel<<<(N + 3) / 4, 256, 0, stream>>>(
        x, u, batch, W1, b1, W2, b2, W3, b3, hb, N);
    seg_bounds_kernel<<<(G + 256) / 256, 256, 0, stream>>>(bh, E, G, seg_start);
    gather_stats_kernel<<<G, 256, 0, stream>>>(hb, hidx, seg_start, Xh, Sinv, out, E);
    mfma_seg_kernel<<<G, 256, 0, stream>>>(
        Xh, seg_start, SWZ, Sinv, c1, c2, V3, c3, out, E);
}

// Round 6
// 375.475 us; speedup vs baseline: 1.5514x; 1.2568x over previous
//
#include <hip/hip_runtime.h>
#include <math.h>

typedef short bf16x8 __attribute__((ext_vector_type(8)));
typedef float f32x4  __attribute__((ext_vector_type(4)));
typedef unsigned short u16;
typedef unsigned int   u32;

#define MFMA16 __builtin_amdgcn_mfma_f32_16x16x32_bf16

__device__ __forceinline__ u16 f2b(float x) {   // fp32 -> bf16 RNE
    union { float f; unsigned u; } v; v.f = x;
    unsigned r = v.u + 0x7fffu + ((v.u >> 16) & 1u);
    return (u16)(r >> 16);
}
__device__ __forceinline__ float b2f(u16 h) {
    union { unsigned u; float f; } v; v.u = ((unsigned)h) << 16;
    return v.f;
}
__device__ __forceinline__ float blo(u32 w) {
    union { u32 u; float f; } v; v.u = w << 16; return v.f;
}
__device__ __forceinline__ float bhi(u32 w) {
    union { u32 u; float f; } v; v.u = w & 0xffff0000u; return v.f;
}

// ---------------------------------------------------------------------------
// K0: pre-swizzle weights (bf16, B-fragment panel layout) into global ws.
// Panel(kt,nt): 16 n-rows x 40 u16 (pad 32->40). SWZ layout:
//   WB [0,5120) | V1B [5120,15360) | V2B [15360,20480)
// ---------------------------------------------------------------------------
__global__ __launch_bounds__(256) void swizzle_weights(
    const float* __restrict__ Wg, const float* __restrict__ V1g,
    const float* __restrict__ V2g, u16* __restrict__ SWZ)
{
    int idx = blockIdx.x * 256 + threadIdx.x;       // 0..8191
    int k = idx >> 6, n = idx & 63;
    int off = ((k >> 5) * 4 + (n >> 4)) * 640 + (n & 15) * 40 + ((k >> 3) & 3) * 8 + (k & 7);
    SWZ[5120 + off] = f2b(V1g[idx]);
    if (idx < 4096) {
        SWZ[off]         = f2b(Wg[idx]);
        SWZ[15360 + off] = f2b(V2g[idx]);
    }
}

// ---------------------------------------------------------------------------
// K1: node MLP -> hb (bf16) [N,64]
// ---------------------------------------------------------------------------
__global__ __launch_bounds__(256) void node_mlp_kernel(
    const float* __restrict__ x, const float* __restrict__ u,
    const int* __restrict__ batch,
    const float* __restrict__ W1, const float* __restrict__ b1,
    const float* __restrict__ W2, const float* __restrict__ b2,
    const float* __restrict__ W3, const float* __restrict__ b3,
    u16* __restrict__ hb, int N)
{
    __shared__ float inbuf[4][10];
    __shared__ float h1[4][64];
    __shared__ float h2[4][64];
    const int tid = threadIdx.x;
    const int ni = tid >> 6, f = tid & 63;
    int node = blockIdx.x * 4 + ni;
    if (node >= N) node = N - 1;
    if (f < 6)       inbuf[ni][f] = x[node * 6 + f];
    else if (f < 10) inbuf[ni][f] = u[batch[node] * 4 + (f - 6)];
    __syncthreads();
    float acc = b1[f];
    #pragma unroll
    for (int k = 0; k < 10; ++k) acc = fmaf(inbuf[ni][k], W1[k * 64 + f], acc);
    h1[ni][f] = fmaxf(acc, 0.f);
    __syncthreads();
    acc = b2[f];
    #pragma unroll 16
    for (int k = 0; k < 64; ++k) acc = fmaf(h1[ni][k], W2[k * 64 + f], acc);
    h2[ni][f] = fmaxf(acc, 0.f);
    __syncthreads();
    acc = b3[f];
    #pragma unroll 16
    for (int k = 0; k < 64; ++k) acc = fmaf(h2[ni][k], W3[k * 64 + f], acc);
    hb[node * 64 + f] = f2b(acc);
}

// ---------------------------------------------------------------------------
// K2: segment boundaries (batch_hyper sorted)
// ---------------------------------------------------------------------------
__global__ __launch_bounds__(256) void seg_bounds_kernel(
    const int* __restrict__ bh, int E, int G, int* __restrict__ seg_start)
{
    int g = blockIdx.x * blockDim.x + threadIdx.x;
    if (g > G) return;
    int lo = 0, hi = E;
    while (lo < hi) {
        int mid = (lo + hi) >> 1;
        if (bh[mid] < g) lo = mid + 1; else hi = mid;
    }
    seg_start[g] = lo;
}

// ---------------------------------------------------------------------------
// K3: gather + Xh write + softmax denominators + out[E..2E) writes.
// 4 edges per wave-iter: sub = lane>>4 picks edge, cl = lane&15 covers 4
// feature cols via uint2 (8B). Explicit unroll-2 -> 6 row-gathers in flight.
// exp() of the ROUNDED bf16 value (must match what K4's MFMA consumes).
// ---------------------------------------------------------------------------
__global__ __launch_bounds__(256) void gather_stats_kernel(
    const u16* __restrict__ hb, const int* __restrict__ hidx,
    const int* __restrict__ seg_start,
    u16* __restrict__ Xh, float* __restrict__ Sinv,
    float* __restrict__ out, int E)
{
    __shared__ float ps[4][16][4];
    const int tid = threadIdx.x, lane = tid & 63, wid = tid >> 6;
    const int sub = lane >> 4, cl = lane & 15;
    const int g = blockIdx.x;
    const int e0 = seg_start[g], e1 = seg_start[g + 1];
    if (e1 <= e0) return;
    const float gf = (float)g;

    for (int e = e0 + tid; e < e1; e += 256) out[E + e] = gf;   // coalesced

    float s0 = 0.f, s1 = 0.f, s2 = 0.f, s3 = 0.f;
    const int base = e0 + wid * 4 + sub;

    for (int e = base; e < e1; e += 32) {
        int eb = e + 16;
        bool h2v = (eb < e1);
        int ai0 = hidx[e], ai1 = hidx[E + e], ai2 = hidx[2 * E + e];
        int bi0 = 0, bi1 = 0, bi2 = 0;
        if (h2v) { bi0 = hidx[eb]; bi1 = hidx[E + eb]; bi2 = hidx[2 * E + eb]; }
        uint2 A0 = *(const uint2*)(hb + (size_t)ai0 * 64 + cl * 4);
        uint2 A1 = *(const uint2*)(hb + (size_t)ai1 * 64 + cl * 4);
        uint2 A2 = *(const uint2*)(hb + (size_t)ai2 * 64 + cl * 4);
        uint2 B0, B1, B2;
        if (h2v) {
            B0 = *(const uint2*)(hb + (size_t)bi0 * 64 + cl * 4);
            B1 = *(const uint2*)(hb + (size_t)bi1 * 64 + cl * 4);
            B2 = *(const uint2*)(hb + (size_t)bi2 * 64 + cl * 4);
        }
        {
            float v0 = blo(A0.x) + blo(A1.x) + blo(A2.x);
            float v1 = bhi(A0.x) + bhi(A1.x) + bhi(A2.x);
            float v2 = blo(A0.y) + blo(A1.y) + blo(A2.y);
            float v3 = bhi(A0.y) + bhi(A1.y) + bhi(A2.y);
            u16 r0 = f2b(v0), r1 = f2b(v1), r2 = f2b(v2), r3 = f2b(v3);
            uint2 W; W.x = (u32)r0 | ((u32)r1 << 16); W.y = (u32)r2 | ((u32)r3 << 16);
            *(uint2*)(Xh + (size_t)e * 64 + cl * 4) = W;
            s0 += __expf(b2f(r0)); s1 += __expf(b2f(r1));
            s2 += __expf(b2f(r2)); s3 += __expf(b2f(r3));
        }
        if (h2v) {
            float v0 = blo(B0.x) + blo(B1.x) + blo(B2.x);
            float v1 = bhi(B0.x) + bhi(B1.x) + bhi(B2.x);
            float v2 = blo(B0.y) + blo(B1.y) + blo(B2.y);
            float v3 = bhi(B0.y) + bhi(B1.y) + bhi(B2.y);
            u16 r0 = f2b(v0), r1 = f2b(v1), r2 = f2b(v2), r3 = f2b(v3);
            uint2 W; W.x = (u32)r0 | ((u32)r1 << 16); W.y = (u32)r2 | ((u32)r3 << 16);
            *(uint2*)(Xh + (size_t)eb * 64 + cl * 4) = W;
            s0 += __expf(b2f(r0)); s1 += __expf(b2f(r1));
            s2 += __expf(b2f(r2)); s3 += __expf(b2f(r3));
        }
    }
    // reduce over sub (lane bits 4,5) then over waves
    s0 += __shfl_xor(s0, 16); s0 += __shfl_xor(s0, 32);
    s1 += __shfl_xor(s1, 16); s1 += __shfl_xor(s1, 32);
    s2 += __shfl_xor(s2, 16); s2 += __shfl_xor(s2, 32);
    s3 += __shfl_xor(s3, 16); s3 += __shfl_xor(s3, 32);
    if (lane < 16) {
        ps[wid][cl][0] = s0; ps[wid][cl][1] = s1;
        ps[wid][cl][2] = s2; ps[wid][cl][3] = s3;
    }
    __syncthreads();
    if (tid < 64) {
        int c4 = tid >> 2, cc = tid & 3;
        float S = ps[0][c4][cc] + ps[1][c4][cc] + ps[2][c4][cc] + ps[3][c4][cc];
        Sinv[g * 64 + tid] = 1.f / S;
    }
}

// ---------------------------------------------------------------------------
// K4: MFMA chain per segment.
//  - ALL weight B-frags (W, V1, V2) in block LDS, staged once per block.
//    R3/R5 post-mortem: V2-in-registers is infeasible at 3 waves/SIMD (the
//    compiler rematerializes as per-tile global reloads = 8KB/tile = 573MB
//    of L2/L3 traffic + an in-chain stall every tile). LDS is the right home.
//  - next-tile Xh a-frags prefetched (HBM latency off the chain).
//  - xv (X in C-layout) via identity-MFMA (exact), no XT round trip for X.
//  - XT used only for Xhat and O1 C->A transposes (wave-private, stride 72).
// LDS: 40960(SW) + 9216(XT) = 50176 B -> 3 blocks/CU (VGPR-bound anyway).
// ---------------------------------------------------------------------------
__global__ __launch_bounds__(256, 3) void mfma_seg_kernel(
    const u16* __restrict__ Xh, const int* __restrict__ seg_start,
    const u16* __restrict__ SWZ, const float* __restrict__ Sinv,
    const float* __restrict__ c1g, const float* __restrict__ c2g,
    const float* __restrict__ V3g, const float* __restrict__ c3g,
    float* __restrict__ out, int E)
{
    __shared__ u16 SW[20480];          // WB[0,5120)+V1B[5120,15360)+V2B[15360,20480)
    __shared__ u16 XT_all[4][16 * 72]; // per-wave transpose tile

    const int tid = threadIdx.x, lane = tid & 63, wid = tid >> 6;
    const int nl = lane & 15, rq = lane >> 4;
    const int g = blockIdx.x;
    const int e0 = seg_start[g], e1 = seg_start[g + 1];
    const int L = e1 - e0;
    if (L <= 0) return;
    const int e1m1 = e1 - 1;

    {   // stage pre-swizzled W+V1+V2: 40960 B = 2560 uint4
        const uint4* src = (const uint4*)SWZ;
        uint4* dst = (uint4*)SW;
        for (int i = tid; i < 2560; i += 256) dst[i] = src[i];
    }
    __syncthreads();
    const u16* WB  = SW;
    const u16* V1B = SW + 5120;
    const u16* V2B = SW + 15360;

    // identity B-frags for X C-layout redistribution (exact in bf16)
    bf16x8 I0, I1;
    #pragma unroll
    for (int j = 0; j < 8; ++j) {
        I0[j] = (rq * 8 + j == nl)      ? (short)0x3F80 : (short)0;
        I1[j] = (rq * 8 + j == nl + 16) ? (short)0x3F80 : (short)0;
    }

    float dinvv[4], c1v[4], c2v[4], v3v[4];
    #pragma unroll
    for (int nt = 0; nt < 4; ++nt) {
        int col = nt * 16 + nl;
        dinvv[nt] = Sinv[g * 64 + col];
        c1v[nt]   = c1g[col];
        c2v[nt]   = c2g[col];
        v3v[nt]   = V3g[col];
    }
    const float c3s = c3g[0];
    u16* XT = XT_all[wid];
    const f32x4 zf = {0.f, 0.f, 0.f, 0.f};

    int t = wid;
    bf16x8 a0 = {}, a1 = {};
    if (t * 16 < L) {
        const u16* xp = Xh + (size_t)min(e0 + t * 16 + nl, e1m1) * 64 + rq * 8;
        a0 = *(const bf16x8*)(xp);
        a1 = *(const bf16x8*)(xp + 32);
    }

    for (; t * 16 < L; t += 4) {
        const int eB = e0 + t * 16;
        const int tn = t + 4;
        bf16x8 n0 = {}, n1 = {};
        if (tn * 16 < L) {  // prefetch next tile (wave-uniform branch)
            const u16* xp = Xh + (size_t)min(e0 + tn * 16 + nl, e1m1) * 64 + rq * 8;
            n0 = *(const bf16x8*)(xp);
            n1 = *(const bf16x8*)(xp + 32);
        }

        // xv in C-layout via identity MFMA (matrix pipe, overlaps layer W)
        f32x4 xc[4];
        xc[0] = MFMA16(a0, I0, zf, 0, 0, 0);
        xc[1] = MFMA16(a0, I1, zf, 0, 0, 0);
        xc[2] = MFMA16(a1, I0, zf, 0, 0, 0);
        xc[3] = MFMA16(a1, I1, zf, 0, 0, 0);

        // ---- layer W: acc = X @ W ----
        f32x4 acc[4] = {zf, zf, zf, zf};
        #pragma unroll
        for (int nt = 0; nt < 4; ++nt) {
            bf16x8 b0 = *(const bf16x8*)(WB + (0 * 4 + nt) * 640 + nl * 40 + rq * 8);
            acc[nt] = MFMA16(a0, b0, acc[nt], 0, 0, 0);
            bf16x8 b1 = *(const bf16x8*)(WB + (1 * 4 + nt) * 640 + nl * 40 + rq * 8);
            acc[nt] = MFMA16(a1, b1, acc[nt], 0, 0, 0);
        }
        // epilogue: Xhat = exp(xv)*dinv * relu(acc) -> XT
        #pragma unroll
        for (int nt = 0; nt < 4; ++nt) {
            #pragma unroll
            for (int r = 0; r < 4; ++r) {
                float coef = __expf(xc[nt][r]) * dinvv[nt];
                XT[(rq * 4 + r) * 72 + nt * 16 + nl] =
                    f2b(coef * fmaxf(acc[nt][r], 0.f));
            }
        }
        bf16x8 x2 = *(const bf16x8*)(XT + nl * 72 + rq * 8);
        bf16x8 x3 = *(const bf16x8*)(XT + nl * 72 + 32 + rq * 8);

        // ---- layer V1: acc2 = [X ; Xhat] @ V1 + c1 ----
        f32x4 acc2[4];
        #pragma unroll
        for (int nt = 0; nt < 4; ++nt) {
            acc2[nt][0] = c1v[nt]; acc2[nt][1] = c1v[nt];
            acc2[nt][2] = c1v[nt]; acc2[nt][3] = c1v[nt];
        }
        #pragma unroll
        for (int nt = 0; nt < 4; ++nt) {
            bf16x8 b0 = *(const bf16x8*)(V1B + (0 * 4 + nt) * 640 + nl * 40 + rq * 8);
            acc2[nt] = MFMA16(a0, b0, acc2[nt], 0, 0, 0);
            bf16x8 b1 = *(const bf16x8*)(V1B + (1 * 4 + nt) * 640 + nl * 40 + rq * 8);
            acc2[nt] = MFMA16(a1, b1, acc2[nt], 0, 0, 0);
        }
        #pragma unroll
        for (int nt = 0; nt < 4; ++nt) {
            bf16x8 b2 = *(const bf16x8*)(V1B + (2 * 4 + nt) * 640 + nl * 40 + rq * 8);
            acc2[nt] = MFMA16(x2, b2, acc2[nt], 0, 0, 0);
            bf16x8 b3 = *(const bf16x8*)(V1B + (3 * 4 + nt) * 640 + nl * 40 + rq * 8);
            acc2[nt] = MFMA16(x3, b3, acc2[nt], 0, 0, 0);
        }
        // epilogue: O1 = relu(acc2) -> XT
        #pragma unroll
        for (int nt = 0; nt < 4; ++nt) {
            #pragma unroll
            for (int r = 0; r < 4; ++r)
                XT[(rq * 4 + r) * 72 + nt * 16 + nl] = f2b(fmaxf(acc2[nt][r], 0.f));
        }
        bf16x8 o0 = *(const bf16x8*)(XT + nl * 72 + rq * 8);
        bf16x8 o1 = *(const bf16x8*)(XT + nl * 72 + 32 + rq * 8);

        // ---- layer V2: acc3 = O1 @ V2 + c2 (B-frags from LDS) ----
        f32x4 acc3[4];
        #pragma unroll
        for (int nt = 0; nt < 4; ++nt) {
            acc3[nt][0] = c2v[nt]; acc3[nt][1] = c2v[nt];
            acc3[nt][2] = c2v[nt]; acc3[nt][3] = c2v[nt];
        }
        #pragma unroll
        for (int nt = 0; nt < 4; ++nt) {
            bf16x8 b0 = *(const bf16x8*)(V2B + (0 * 4 + nt) * 640 + nl * 40 + rq * 8);
            acc3[nt] = MFMA16(o0, b0, acc3[nt], 0, 0, 0);
            bf16x8 b1 = *(const bf16x8*)(V2B + (1 * 4 + nt) * 640 + nl * 40 + rq * 8);
            acc3[nt] = MFMA16(o1, b1, acc3[nt], 0, 0, 0);
        }

        // ---- V3 + sigmoid ----
        float sr[4];
        #pragma unroll
        for (int r = 0; r < 4; ++r) {
            float v = 0.f;
            #pragma unroll
            for (int nt = 0; nt < 4; ++nt)
                v = fmaf(fmaxf(acc3[nt][r], 0.f), v3v[nt], v);
            v += __shfl_xor(v, 1);
            v += __shfl_xor(v, 2);
            v += __shfl_xor(v, 4);
            v += __shfl_xor(v, 8);
            sr[r] = v;
        }
        if (nl == 0) {
            #pragma unroll
            for (int r = 0; r < 4; ++r) {
                int e = eB + rq * 4 + r;
                if (e < e1) out[e] = 1.f / (1.f + __expf(-(sr[r] + c3s)));
            }
        }
        a0 = n0; a1 = n1;
    }
}

// ---------------------------------------------------------------------------
extern "C" void kernel_launch(void* const* d_in, const int* in_sizes, int n_in,
                              void* d_out, int out_size, void* d_ws, size_t ws_size,
                              hipStream_t stream) {
    const float* x     = (const float*)d_in[0];
    const float* u     = (const float*)d_in[1];
    const int*   batch = (const int*)  d_in[2];
    const int*   hidx  = (const int*)  d_in[3];
    const int*   bh    = (const int*)  d_in[4];
    const float* W1 = (const float*)d_in[6];
    const float* b1 = (const float*)d_in[7];
    const float* W2 = (const float*)d_in[8];
    const float* b2 = (const float*)d_in[9];
    const float* W3 = (const float*)d_in[10];
    const float* b3 = (const float*)d_in[11];
    const float* Wg = (const float*)d_in[12];
    const float* V1 = (const float*)d_in[13];
    const float* c1 = (const float*)d_in[14];
    const float* V2 = (const float*)d_in[15];
    const float* c2 = (const float*)d_in[16];
    const float* V3 = (const float*)d_in[17];
    const float* c3 = (const float*)d_in[18];

    const int N = in_sizes[0] / 6;
    const int G = in_sizes[1] / 4;
    const int E = in_sizes[4];

    // ws layout
    char* ws = (char*)d_ws;
    size_t off = 0;
    u16* hb = (u16*)(ws + off);            off += (size_t)N * 64 * 2;
    int* seg_start = (int*)(ws + off);     off += ((size_t)G + 1) * 4;
    off = (off + 255) & ~(size_t)255;
    u16* SWZ = (u16*)(ws + off);           off += 20480 * 2;
    float* Sinv = (float*)(ws + off);      off += (size_t)G * 64 * 4;
    off = (off + 255) & ~(size_t)255;
    u16* Xh = (u16*)(ws + off);            off += (size_t)E * 64 * 2;
    float* out = (float*)d_out;

    swizzle_weights<<<32, 256, 0, stream>>>(Wg, V1, V2, SWZ);
    node_mlp_kernel<<<(N + 3) / 4, 256, 0, stream>>>(
        x, u, batch, W1, b1, W2, b2, W3, b3, hb, N);
    seg_bounds_kernel<<<(G + 256) / 256, 256, 0, stream>>>(bh, E, G, seg_start);
    gather_stats_kernel<<<G, 256, 0, stream>>>(hb, hidx, seg_start, Xh, Sinv, out, E);
    mfma_seg_kernel<<<G, 256, 0, stream>>>(
        Xh, seg_start, SWZ, Sinv, c1, c2, V3, c3, out, E);
}